// Round 1
// baseline (48664.624 us; speedup 1.0000x reference)
//
#include <hip/hip_runtime.h>
#include <hip/hip_bf16.h>
#include <math.h>

typedef unsigned long long u64;

// Sizes
#define N_NODES 8192
#define IN_DIM 64
#define MLP_HID 128
#define EMB 512
#define HID 1024
#define G3 (3*HID)   // 3072
#define SEQ 8192

// ---------------------------------------------------------------------------
// Expert MLP: one block per node. h1 = relu(x@W1[t]+b1[t]); emb = h1@W2[t]+b2[t]
// ---------------------------------------------------------------------------
__global__ __launch_bounds__(256) void mlp_kernel(
    const float* __restrict__ x, const int* __restrict__ types,
    const float* __restrict__ W1, const float* __restrict__ b1,
    const float* __restrict__ W2, const float* __restrict__ b2,
    float* __restrict__ emb)
{
    __shared__ float xs[IN_DIM];
    __shared__ float h1[MLP_HID];
    const int n = blockIdx.x;
    const int ty = types[n];
    const int tid = threadIdx.x;

    if (tid < IN_DIM) xs[tid] = x[n * IN_DIM + tid];
    __syncthreads();

    if (tid < MLP_HID) {
        const float* w = W1 + (size_t)ty * IN_DIM * MLP_HID;
        float acc = b1[ty * MLP_HID + tid];
        #pragma unroll 8
        for (int k = 0; k < IN_DIM; k++)
            acc += xs[k] * w[k * MLP_HID + tid];
        h1[tid] = fmaxf(acc, 0.f);
    }
    __syncthreads();

    const float* w2 = W2 + (size_t)ty * MLP_HID * EMB;
    #pragma unroll
    for (int j = tid; j < EMB; j += 256) {
        float acc = b2[ty * EMB + j];
        #pragma unroll 8
        for (int k = 0; k < MLP_HID; k++)
            acc += h1[k] * w2[k * EMB + j];
        emb[(size_t)n * EMB + j] = acc;
    }
}

// ---------------------------------------------------------------------------
// C[M,N] = A[M,K] @ B[N,K]^T + bias[N]   (fp32, 64x64 tile, BK=16)
// ---------------------------------------------------------------------------
#define BM 64
#define BN 64
#define BK 16
__global__ __launch_bounds__(256) void gemm_bt_bias(
    const float* __restrict__ A, const float* __restrict__ B,
    const float* __restrict__ bias, float* __restrict__ C,
    int M, int N, int K)
{
    __shared__ float As[BK][BM + 1];
    __shared__ float Bs[BK][BN + 1];
    const int bm = blockIdx.y * BM, bn = blockIdx.x * BN;
    const int tid = threadIdx.x;
    const int tx = tid & 15, tyy = tid >> 4;   // 16x16 thread grid
    const int lr = tid >> 2;                   // loader row 0..63
    const int lk = (tid & 3) * 4;              // loader k offset

    float acc[4][4] = {};

    for (int k0 = 0; k0 < K; k0 += BK) {
        float4 av = *(const float4*)(A + (size_t)(bm + lr) * K + k0 + lk);
        float4 bv = *(const float4*)(B + (size_t)(bn + lr) * K + k0 + lk);
        As[lk + 0][lr] = av.x; As[lk + 1][lr] = av.y;
        As[lk + 2][lr] = av.z; As[lk + 3][lr] = av.w;
        Bs[lk + 0][lr] = bv.x; Bs[lk + 1][lr] = bv.y;
        Bs[lk + 2][lr] = bv.z; Bs[lk + 3][lr] = bv.w;
        __syncthreads();
        #pragma unroll
        for (int k = 0; k < BK; k++) {
            float a[4], b[4];
            #pragma unroll
            for (int i = 0; i < 4; i++) a[i] = As[k][tyy * 4 + i];
            #pragma unroll
            for (int j = 0; j < 4; j++) b[j] = Bs[k][tx * 4 + j];
            #pragma unroll
            for (int i = 0; i < 4; i++)
                #pragma unroll
                for (int j = 0; j < 4; j++)
                    acc[i][j] += a[i] * b[j];
        }
        __syncthreads();
    }

    #pragma unroll
    for (int i = 0; i < 4; i++) {
        const int row = bm + tyy * 4 + i;
        #pragma unroll
        for (int j = 0; j < 4; j++) {
            const int col = bn + tx * 4 + j;
            C[(size_t)row * N + col] = acc[i][j] + bias[col];
        }
    }
}

// ---------------------------------------------------------------------------
// Fused 2-layer GRU scan. 256 blocks (1/CU); block b's wave wv owns dim
// d = 4b+wv of both layers. Weights LDS-resident (R5).
//
// R9 sync: SPLIT-PHASE exchange (poll hbuf0 -> compute/publish h0 -> poll
// hbuf1 -> compute/publish h1), per-word epoch tags, depth-2 ring, relaxed
// agent-scope 8B atomics, pending-mask parallel poll + s_sleep backoff.
//
// R10: SOFTWARE-PIPELINED POLLS. The coherent (agent-scope) loads cost
// ~700cy each way because per-XCD L2 can't serve them; issuing them at the
// point of consumption exposed that latency twice per step. Now:
//   - next-A prefetch (hbuf0 slot e&1, tag e) is issued right after S2,
//     so its latency rides under phase D's compute.
//   - next-C prefetch (hbuf1 slot e&1, tag e) is issued at loop end (after
//     D's publish), riding under next epoch's A+B. Its target was published
//     a full loop ago by the time it's checked -> near-guaranteed hit.
// The check consumes the prefetched registers; any stale tag falls back to
// the exact same pending-mask reload loop as before (cost identical to the
// old round-1), so this is monotone-safe. Only load ISSUE points moved:
// tag protocol, publish points, barriers, and the anti-lap argument are
// unchanged (an early read that sees a stale tag just retries; the success
// conditions that gate writers are exactly where they were).
//
// Anti-lap per buffer: block X posts tag e into slot e&1 only after S1/S2,
// i.e. after ALL X's threads saw every tag e-1 — and any block Y posted
// tag e-1 only after Y's S1/S2 guaranteed Y's tag e-2 reads (same slot)
// retired. Barriers: S1 after hl0 fill, S2 after hl1 fill; hr0 reads
// precede S2, hr1 reads precede next epoch's S1, so LDS reuse is race-free.
// ---------------------------------------------------------------------------
#define WLDS_FLOATS (36 * 1024)          // 147456 B
#define HL0_OFF WLDS_FLOATS
#define HL1_OFF (WLDS_FLOATS + HID)

__global__ __launch_bounds__(256, 1) void gru_fused(
    const float* __restrict__ gi0,   // [T, 3072] layer-0 input gates (incl. bih0)
    const float* __restrict__ Whh0, const float* __restrict__ bhh0,
    const float* __restrict__ Wih1, const float* __restrict__ bih1,
    const float* __restrict__ Whh1, const float* __restrict__ bhh1,
    const float* __restrict__ h_init,   // [2, 1024]
    u64* __restrict__ hbuf0,            // [2][1024] tagged ring, layer 0
    u64* __restrict__ hbuf1,            // [2][1024] tagged ring, layer 1
    float* __restrict__ hout,           // [1024] final h1
    int T)
{
    __shared__ float lds[WLDS_FLOATS + 2 * HID];   // 155648 B

    const int tid = threadIdx.x;
    const int b = blockIdx.x;
    const int wv = tid >> 6;
    const int lane = tid & 63;
    const int d = b * 4 + wv;

    float* hl0 = &lds[HL0_OFF];
    float* hl1 = &lds[HL1_OFF];

    // ---- stage 36 weight rows into LDS (once) ----
    for (int p = 0; p < 36; p++) {
        const int dl = p / 9, r = p % 9;
        const int m = r / 3, g = r % 3;
        const float* src = (m == 0 ? Whh0 : (m == 1 ? Wih1 : Whh1))
                           + (size_t)(g * HID + b * 4 + dl) * HID;
        float4* dst = (float4*)&lds[(dl * 9 + r) * HID];
        dst[tid] = ((const float4*)src)[tid];
    }
    __syncthreads();

    const float bh00 = bhh0[d], bh01 = bhh0[HID + d], bh02 = bhh0[2 * HID + d];
    const float bi10 = bih1[d], bi11 = bih1[HID + d], bi12 = bih1[2 * HID + d];
    const float bh10 = bhh1[d], bh11 = bhh1[HID + d], bh12 = bhh1[2 * HID + d];

    float hprev0 = 0.f, hprev1 = 0.f;
    float gc0 = 0.f, gc1 = 0.f, gc2 = 0.f;
    if (lane == 0) {
        hprev0 = h_init[d];
        hprev1 = h_init[HID + d];
        gc0 = gi0[d]; gc1 = gi0[HID + d]; gc2 = gi0[2 * HID + d];
    }

    // Prefetched exchange words (tag 0 never matches any epoch in [1,T+1]).
    u64 va[4] = {0, 0, 0, 0};   // next phase-A words (hbuf0)
    u64 vb[4] = {0, 0, 0, 0};   // next phase-C words (hbuf1)

    for (int e = 1; e <= T + 1; e++) {
        // Prefetch next epoch's gi0 row (in flight under the exchanges).
        float gn0 = 0.f, gn1 = 0.f, gn2 = 0.f;
        if (lane == 0 && e < T) {
            const float* g = gi0 + (size_t)e * G3;
            gn0 = g[d]; gn1 = g[HID + d]; gn2 = g[2 * HID + d];
        }

        // ===== PHASE A: layer-0 h exchange (critical chain) =====
        if (e == 1) {
            #pragma unroll
            for (int j = 0; j < 4; j++)
                hl0[tid + 256 * j] = h_init[tid + 256 * j];
            __syncthreads();   // S1
        } else {
            const unsigned te = (unsigned)(e - 1);
            bool dn[4];
            bool okA = true;
            #pragma unroll
            for (int j = 0; j < 4; j++) {
                dn[j] = ((unsigned)(va[j] >> 32) == te);
                okA &= dn[j];
            }
            if (!okA) {
                const u64* sa = hbuf0 + ((e - 1) & 1) * HID;
                for (;;) {
                    #pragma unroll
                    for (int j = 0; j < 4; j++)
                        if (!dn[j])
                            va[j] = __hip_atomic_load(&sa[tid + 256 * j], __ATOMIC_RELAXED,
                                                      __HIP_MEMORY_SCOPE_AGENT);
                    bool ok = true;
                    #pragma unroll
                    for (int j = 0; j < 4; j++) {
                        dn[j] = dn[j] || ((unsigned)(va[j] >> 32) == te);
                        ok &= dn[j];
                    }
                    if (ok) break;
                    __builtin_amdgcn_s_sleep(1);   // backoff: tame the poll storm
                }
            }
            #pragma unroll
            for (int j = 0; j < 4; j++)
                hl0[tid + 256 * j] = __uint_as_float((unsigned)va[j]);
            __syncthreads();   // S1: all poll0 loads retired block-wide
        }

        const float4* h0v4 = (const float4*)hl0;
        float4 hr0[4];
        #pragma unroll
        for (int j = 0; j < 4; j++) hr0[j] = h0v4[64 * j + lane];

        // ===== PHASE B: layer-0 compute + publish =====
        if (e <= T) {
            float s[3];
            #pragma unroll
            for (int g = 0; g < 3; g++) {
                const float4* wr = (const float4*)&lds[(wv * 9 + g) * HID];
                float4 a = {0.f, 0.f, 0.f, 0.f};
                #pragma unroll
                for (int j = 0; j < 4; j++) {
                    float4 w = wr[64 * j + lane];
                    a.x += w.x * hr0[j].x; a.y += w.y * hr0[j].y;
                    a.z += w.z * hr0[j].z; a.w += w.w * hr0[j].w;
                }
                float acc = (a.x + a.y) + (a.z + a.w);
                #pragma unroll
                for (int off = 32; off; off >>= 1)
                    acc += __shfl_down(acc, off, 64);
                s[g] = acc;
            }
            if (lane == 0) {
                const float r = 1.f / (1.f + __expf(-(gc0 + s[0] + bh00)));
                const float z = 1.f / (1.f + __expf(-(gc1 + s[1] + bh01)));
                const float nn = tanhf(gc2 + r * (s[2] + bh02));
                const float hnew = (1.f - z) * nn + z * hprev0;
                hprev0 = hnew;
                const u64 v = ((u64)(unsigned)e << 32) | (u64)__float_as_uint(hnew);
                __hip_atomic_store(&hbuf0[(e & 1) * HID + d], v,
                                   __ATOMIC_RELAXED, __HIP_MEMORY_SCOPE_AGENT);
                gc0 = gn0; gc1 = gn1; gc2 = gn2;
            }
        }

        // ===== PHASE C: layer-1 h exchange (prefetched; in layer-0's shadow) =====
        if (e == 1) {
            if (lane == 0) {
                const u64 v = ((u64)1u << 32) | (u64)__float_as_uint(hprev1);
                __hip_atomic_store(&hbuf1[HID + d], v,
                                   __ATOMIC_RELAXED, __HIP_MEMORY_SCOPE_AGENT);
            }
            __syncthreads();   // protect hl0 reads vs next epoch's writes
        } else {
            const unsigned te = (unsigned)(e - 1);
            bool dn[4];
            bool okC = true;
            #pragma unroll
            for (int j = 0; j < 4; j++) {
                dn[j] = ((unsigned)(vb[j] >> 32) == te);
                okC &= dn[j];
            }
            if (!okC) {
                const u64* sb = hbuf1 + ((e - 1) & 1) * HID;
                for (;;) {
                    #pragma unroll
                    for (int j = 0; j < 4; j++)
                        if (!dn[j])
                            vb[j] = __hip_atomic_load(&sb[tid + 256 * j], __ATOMIC_RELAXED,
                                                      __HIP_MEMORY_SCOPE_AGENT);
                    bool ok = true;
                    #pragma unroll
                    for (int j = 0; j < 4; j++) {
                        dn[j] = dn[j] || ((unsigned)(vb[j] >> 32) == te);
                        ok &= dn[j];
                    }
                    if (ok) break;
                    __builtin_amdgcn_s_sleep(1);
                }
            }
            #pragma unroll
            for (int j = 0; j < 4; j++)
                hl1[tid + 256 * j] = __uint_as_float((unsigned)vb[j]);
            __syncthreads();   // S2: all poll1 loads retired block-wide
        }

        // ---- issue next-A prefetch (hbuf0 slot e&1, tag e); rides under D ----
        if (e <= T) {
            const u64* pa = hbuf0 + (e & 1) * HID;
            #pragma unroll
            for (int j = 0; j < 4; j++)
                va[j] = __hip_atomic_load(&pa[tid + 256 * j], __ATOMIC_RELAXED,
                                          __HIP_MEMORY_SCOPE_AGENT);
        }

        // ===== PHASE D: layer-1 compute + publish =====
        if (e >= 2) {
            const float4* h1v4 = (const float4*)hl1;
            float4 hr1[4];
            #pragma unroll
            for (int j = 0; j < 4; j++) hr1[j] = h1v4[64 * j + lane];

            float si[3], sh[3];
            #pragma unroll
            for (int g = 0; g < 3; g++) {
                const float4* wi = (const float4*)&lds[(wv * 9 + 3 + g) * HID];
                const float4* wh = (const float4*)&lds[(wv * 9 + 6 + g) * HID];
                float4 a = {0.f, 0.f, 0.f, 0.f};
                float4 c = {0.f, 0.f, 0.f, 0.f};
                #pragma unroll
                for (int j = 0; j < 4; j++) {
                    float4 w1 = wi[64 * j + lane];
                    float4 w2 = wh[64 * j + lane];
                    a.x += w1.x * hr0[j].x; a.y += w1.y * hr0[j].y;
                    a.z += w1.z * hr0[j].z; a.w += w1.w * hr0[j].w;
                    c.x += w2.x * hr1[j].x; c.y += w2.y * hr1[j].y;
                    c.z += w2.z * hr1[j].z; c.w += w2.w * hr1[j].w;
                }
                float ai = (a.x + a.y) + (a.z + a.w);
                float ch = (c.x + c.y) + (c.z + c.w);
                #pragma unroll
                for (int off = 32; off; off >>= 1) {
                    ai += __shfl_down(ai, off, 64);
                    ch += __shfl_down(ch, off, 64);
                }
                si[g] = ai; sh[g] = ch;
            }
            if (lane == 0) {
                const float r = 1.f / (1.f + __expf(-(si[0] + bi10 + sh[0] + bh10)));
                const float z = 1.f / (1.f + __expf(-(si[1] + bi11 + sh[1] + bh11)));
                const float nn = tanhf(si[2] + bi12 + r * (sh[2] + bh12));
                const float hnew = (1.f - z) * nn + z * hprev1;
                hprev1 = hnew;
                if (e <= T) {
                    const u64 v = ((u64)(unsigned)e << 32) | (u64)__float_as_uint(hnew);
                    __hip_atomic_store(&hbuf1[(e & 1) * HID + d], v,
                                       __ATOMIC_RELAXED, __HIP_MEMORY_SCOPE_AGENT);
                } else {
                    hout[d] = hnew;   // e == T+1: final h1
                }
            }
        }

        // ---- issue next-C prefetch (hbuf1 slot e&1, tag e); rides under A+B ----
        if (e <= T) {
            const u64* pb = hbuf1 + (e & 1) * HID;
            #pragma unroll
            for (int j = 0; j < 4; j++)
                vb[j] = __hip_atomic_load(&pb[tid + 256 * j], __ATOMIC_RELAXED,
                                          __HIP_MEMORY_SCOPE_AGENT);
        }
    }
}

// ---------------------------------------------------------------------------
// out[o] = dot(fc_W[o,:], h) + fc_b[o]; 64 waves, 16 outputs each.
// ---------------------------------------------------------------------------
__global__ __launch_bounds__(256) void fc_kernel(
    const float* __restrict__ h, const float* __restrict__ W,
    const float* __restrict__ b, float* __restrict__ out)
{
    __shared__ float hs[HID];
    const int wv = blockIdx.x * 4 + (threadIdx.x >> 6);
    const int lane = threadIdx.x & 63;
    for (int i = threadIdx.x; i < HID; i += 256) hs[i] = h[i];
    __syncthreads();
    for (int o = wv * 16; o < wv * 16 + 16; o++) {
        float acc = 0.f;
        #pragma unroll
        for (int u = 0; u < 16; u++)
            acc += W[(size_t)o * HID + lane + 64 * u] * hs[lane + 64 * u];
        #pragma unroll
        for (int off = 32; off; off >>= 1)
            acc += __shfl_down(acc, off, 64);
        if (lane == 0) out[o] = acc + b[o];
    }
}

// ---------------------------------------------------------------------------
extern "C" void kernel_launch(void* const* d_in, const int* in_sizes, int n_in,
                              void* d_out, int out_size, void* d_ws, size_t ws_size,
                              hipStream_t stream)
{
    const float* node_feats = (const float*)d_in[0];
    const int*   node_types = (const int*)d_in[1];
    const float* W1   = (const float*)d_in[2];
    const float* b1   = (const float*)d_in[3];
    const float* W2   = (const float*)d_in[4];
    const float* b2   = (const float*)d_in[5];
    const float* Wih0 = (const float*)d_in[6];
    const float* Whh0 = (const float*)d_in[7];
    const float* bih0 = (const float*)d_in[8];
    const float* bhh0 = (const float*)d_in[9];
    const float* Wih1 = (const float*)d_in[10];
    const float* Whh1 = (const float*)d_in[11];
    const float* bih1 = (const float*)d_in[12];
    const float* bhh1 = (const float*)d_in[13];
    const float* h_init = (const float*)d_in[14];
    const float* fc_W = (const float*)d_in[15];
    const float* fc_b = (const float*)d_in[16];
    float* out = (float*)d_out;

    char* ws = (char*)d_ws;
    const size_t GI_OFF    = 0;                      // 8192*3072*4 = 100663296
    const size_t EMB_OFF   = 100663296;              // 8192*512*4  = 16777216
    const size_t HOUT_OFF  = 117440512;              // 1024*4      = 4096
    const size_t HBUF0_OFF = 117444608;              // 2048*8      = 16384
    const size_t HBUF1_OFF = 117460992;              // 2048*8      = 16384

    float* gi   = (float*)(ws + GI_OFF);
    float* emb  = (float*)(ws + EMB_OFF);
    float* hout = (float*)(ws + HOUT_OFF);
    u64* hbuf0  = (u64*)(ws + HBUF0_OFF);
    u64* hbuf1  = (u64*)(ws + HBUF1_OFF);
    // hbufs start 0xAA-poisoned: tag 0xAAAAAAAA never matches an epoch in
    // [1, 8193], so no memset needed anywhere.

    // 1. Expert MLP -> emb [8192, 512]
    mlp_kernel<<<N_NODES, 256, 0, stream>>>(node_feats, node_types, W1, b1, W2, b2, emb);

    // 2. gi0 = emb @ Wih0^T + bih0  [8192, 3072]
    gemm_bt_bias<<<dim3(G3 / BN, N_NODES / BM), 256, 0, stream>>>(
        emb, Wih0, bih0, gi, N_NODES, G3, EMB);

    // 3. fused 2-layer scan (split-phase, software-pipelined exchange)
    gru_fused<<<256, 256, 0, stream>>>(gi, Whh0, bhh0, Wih1, bih1, Whh1, bhh1,
                                       h_init, hbuf0, hbuf1, hout, SEQ);

    // 4. FC on final hidden state
    fc_kernel<<<16, 256, 0, stream>>>(hout, fc_W, fc_b, out);
}

// Round 2
// 28693.579 us; speedup vs baseline: 1.6960x; 1.6960x over previous
//
#include <hip/hip_runtime.h>
#include <hip/hip_bf16.h>
#include <math.h>

typedef unsigned long long u64;

// Sizes
#define N_NODES 8192
#define IN_DIM 64
#define MLP_HID 128
#define EMB 512
#define HID 1024
#define G3 (3*HID)   // 3072
#define SEQ 8192

// ---------------------------------------------------------------------------
// Expert MLP: one block per node. h1 = relu(x@W1[t]+b1[t]); emb = h1@W2[t]+b2[t]
// ---------------------------------------------------------------------------
__global__ __launch_bounds__(256) void mlp_kernel(
    const float* __restrict__ x, const int* __restrict__ types,
    const float* __restrict__ W1, const float* __restrict__ b1,
    const float* __restrict__ W2, const float* __restrict__ b2,
    float* __restrict__ emb)
{
    __shared__ float xs[IN_DIM];
    __shared__ float h1[MLP_HID];
    const int n = blockIdx.x;
    const int ty = types[n];
    const int tid = threadIdx.x;

    if (tid < IN_DIM) xs[tid] = x[n * IN_DIM + tid];
    __syncthreads();

    if (tid < MLP_HID) {
        const float* w = W1 + (size_t)ty * IN_DIM * MLP_HID;
        float acc = b1[ty * MLP_HID + tid];
        #pragma unroll 8
        for (int k = 0; k < IN_DIM; k++)
            acc += xs[k] * w[k * MLP_HID + tid];
        h1[tid] = fmaxf(acc, 0.f);
    }
    __syncthreads();

    const float* w2 = W2 + (size_t)ty * MLP_HID * EMB;
    #pragma unroll
    for (int j = tid; j < EMB; j += 256) {
        float acc = b2[ty * EMB + j];
        #pragma unroll 8
        for (int k = 0; k < MLP_HID; k++)
            acc += h1[k] * w2[k * EMB + j];
        emb[(size_t)n * EMB + j] = acc;
    }
}

// ---------------------------------------------------------------------------
// C[M,N] = A[M,K] @ B[N,K]^T + bias[N]   (fp32, 64x64 tile, BK=16)
// ---------------------------------------------------------------------------
#define BM 64
#define BN 64
#define BK 16
__global__ __launch_bounds__(256) void gemm_bt_bias(
    const float* __restrict__ A, const float* __restrict__ B,
    const float* __restrict__ bias, float* __restrict__ C,
    int M, int N, int K)
{
    __shared__ float As[BK][BM + 1];
    __shared__ float Bs[BK][BN + 1];
    const int bm = blockIdx.y * BM, bn = blockIdx.x * BN;
    const int tid = threadIdx.x;
    const int tx = tid & 15, tyy = tid >> 4;   // 16x16 thread grid
    const int lr = tid >> 2;                   // loader row 0..63
    const int lk = (tid & 3) * 4;              // loader k offset

    float acc[4][4] = {};

    for (int k0 = 0; k0 < K; k0 += BK) {
        float4 av = *(const float4*)(A + (size_t)(bm + lr) * K + k0 + lk);
        float4 bv = *(const float4*)(B + (size_t)(bn + lr) * K + k0 + lk);
        As[lk + 0][lr] = av.x; As[lk + 1][lr] = av.y;
        As[lk + 2][lr] = av.z; As[lk + 3][lr] = av.w;
        Bs[lk + 0][lr] = bv.x; Bs[lk + 1][lr] = bv.y;
        Bs[lk + 2][lr] = bv.z; Bs[lk + 3][lr] = bv.w;
        __syncthreads();
        #pragma unroll
        for (int k = 0; k < BK; k++) {
            float a[4], b[4];
            #pragma unroll
            for (int i = 0; i < 4; i++) a[i] = As[k][tyy * 4 + i];
            #pragma unroll
            for (int j = 0; j < 4; j++) b[j] = Bs[k][tx * 4 + j];
            #pragma unroll
            for (int i = 0; i < 4; i++)
                #pragma unroll
                for (int j = 0; j < 4; j++)
                    acc[i][j] += a[i] * b[j];
        }
        __syncthreads();
    }

    #pragma unroll
    for (int i = 0; i < 4; i++) {
        const int row = bm + tyy * 4 + i;
        #pragma unroll
        for (int j = 0; j < 4; j++) {
            const int col = bn + tx * 4 + j;
            C[(size_t)row * N + col] = acc[i][j] + bias[col];
        }
    }
}

// ---------------------------------------------------------------------------
// Fused 2-layer GRU scan. 256 blocks (1/CU); block b's wave wv owns dim
// d = 4b+wv of both layers. Weights LDS-resident (R5).
//
// R9 sync: SPLIT-PHASE exchange. Layer-0's recurrence is the only true
// serial chain, so each epoch: poll hbuf0 -> compute & publish h0 -> poll
// hbuf1 -> compute & publish h1. Per-word epoch tags, depth-2 ring,
// relaxed agent-scope 8B atomics, pending-mask parallel poll + s_sleep
// backoff after a failed round.
//
// R11: phase-C's ROUND-1 loads are RELOCATED (not duplicated — R10's
// duplicated prefetch doubled coherent-load count, FETCH 991->2249 MB,
// and collapsed 30.7->48.7 ms by warming stale L2 lines) to just after
// S1, before phase-B compute. Phase-A success at epoch e guarantees every
// block finished B of e-1, i.e. is at/past C of e-1 — so hbuf1 tag e-1
// (published in D of e-1) is present for all but a ~1-2k-cycle laggard
// tail. The ~700cy RTT rides under B's compute; stale words fall into the
// UNCHANGED pending-mask fallback at the original point (worst case ==
// R9's round 1). Total coherent loads per step are identical to R9.
//
// Anti-lap per buffer: block X posts tag e into slot e&1 only after S1/S2,
// i.e. after ALL X's threads saw every tag e-1 — and any block Y posted
// tag e-1 only after Y's S1/S2 guaranteed Y's tag e-2 reads (same slot)
// retired. The relocated C loads' consumed values all retire before the
// hl1 fill that precedes S2, so the gating is unchanged; a future tag e+1
// in the polled slot is impossible at issue time (it requires every
// block's S2 of epoch e, which requires this very check). Barriers: S1
// after hl0 fill, S2 after hl1 fill; hr0 reads precede S2, hr1 reads
// precede next epoch's S1, so LDS reuse is race-free.
// ---------------------------------------------------------------------------
#define WLDS_FLOATS (36 * 1024)          // 147456 B
#define HL0_OFF WLDS_FLOATS
#define HL1_OFF (WLDS_FLOATS + HID)

__global__ __launch_bounds__(256, 1) void gru_fused(
    const float* __restrict__ gi0,   // [T, 3072] layer-0 input gates (incl. bih0)
    const float* __restrict__ Whh0, const float* __restrict__ bhh0,
    const float* __restrict__ Wih1, const float* __restrict__ bih1,
    const float* __restrict__ Whh1, const float* __restrict__ bhh1,
    const float* __restrict__ h_init,   // [2, 1024]
    u64* __restrict__ hbuf0,            // [2][1024] tagged ring, layer 0
    u64* __restrict__ hbuf1,            // [2][1024] tagged ring, layer 1
    float* __restrict__ hout,           // [1024] final h1
    int T)
{
    __shared__ float lds[WLDS_FLOATS + 2 * HID];   // 155648 B

    const int tid = threadIdx.x;
    const int b = blockIdx.x;
    const int wv = tid >> 6;
    const int lane = tid & 63;
    const int d = b * 4 + wv;

    float* hl0 = &lds[HL0_OFF];
    float* hl1 = &lds[HL1_OFF];

    // ---- stage 36 weight rows into LDS (once) ----
    for (int p = 0; p < 36; p++) {
        const int dl = p / 9, r = p % 9;
        const int m = r / 3, g = r % 3;
        const float* src = (m == 0 ? Whh0 : (m == 1 ? Wih1 : Whh1))
                           + (size_t)(g * HID + b * 4 + dl) * HID;
        float4* dst = (float4*)&lds[(dl * 9 + r) * HID];
        dst[tid] = ((const float4*)src)[tid];
    }
    __syncthreads();

    const float bh00 = bhh0[d], bh01 = bhh0[HID + d], bh02 = bhh0[2 * HID + d];
    const float bi10 = bih1[d], bi11 = bih1[HID + d], bi12 = bih1[2 * HID + d];
    const float bh10 = bhh1[d], bh11 = bhh1[HID + d], bh12 = bhh1[2 * HID + d];

    float hprev0 = 0.f, hprev1 = 0.f;
    float gc0 = 0.f, gc1 = 0.f, gc2 = 0.f;
    if (lane == 0) {
        hprev0 = h_init[d];
        hprev1 = h_init[HID + d];
        gc0 = gi0[d]; gc1 = gi0[HID + d]; gc2 = gi0[2 * HID + d];
    }

    for (int e = 1; e <= T + 1; e++) {
        // Prefetch next epoch's gi0 row (in flight under the polls).
        float gn0 = 0.f, gn1 = 0.f, gn2 = 0.f;
        if (lane == 0 && e < T) {
            const float* g = gi0 + (size_t)e * G3;
            gn0 = g[d]; gn1 = g[HID + d]; gn2 = g[2 * HID + d];
        }

        // ===== PHASE A: layer-0 h exchange (critical chain) =====
        if (e == 1) {
            #pragma unroll
            for (int j = 0; j < 4; j++)
                hl0[tid + 256 * j] = h_init[tid + 256 * j];
            __syncthreads();   // S1
        } else {
            const unsigned te = (unsigned)(e - 1);
            const u64* sa = hbuf0 + ((e - 1) & 1) * HID;
            u64 va[4];
            bool dn[4] = {false, false, false, false};
            for (;;) {
                #pragma unroll
                for (int j = 0; j < 4; j++)
                    if (!dn[j])
                        va[j] = __hip_atomic_load(&sa[tid + 256 * j], __ATOMIC_RELAXED,
                                                  __HIP_MEMORY_SCOPE_AGENT);
                bool ok = true;
                #pragma unroll
                for (int j = 0; j < 4; j++) {
                    dn[j] = dn[j] || ((unsigned)(va[j] >> 32) == te);
                    ok &= dn[j];
                }
                if (ok) break;
                __builtin_amdgcn_s_sleep(1);   // backoff: tame the poll storm
            }
            #pragma unroll
            for (int j = 0; j < 4; j++)
                hl0[tid + 256 * j] = __uint_as_float((unsigned)va[j]);
            __syncthreads();   // S1: all poll0 loads retired block-wide
        }

        // ---- phase-C round 1, RELOCATED: issue now so the ~700cy RTT
        //      rides under phase-B's compute. Same loads as R9's round 1,
        //      just earlier (within the same-epoch skew window). ----
        u64 vc[4] = {0, 0, 0, 0};
        if (e >= 2) {
            const u64* sb = hbuf1 + ((e - 1) & 1) * HID;
            #pragma unroll
            for (int j = 0; j < 4; j++)
                vc[j] = __hip_atomic_load(&sb[tid + 256 * j], __ATOMIC_RELAXED,
                                          __HIP_MEMORY_SCOPE_AGENT);
        }

        const float4* h0v4 = (const float4*)hl0;
        float4 hr0[4];
        #pragma unroll
        for (int j = 0; j < 4; j++) hr0[j] = h0v4[64 * j + lane];

        // ===== PHASE B: layer-0 compute + publish =====
        if (e <= T) {
            float s[3];
            #pragma unroll
            for (int g = 0; g < 3; g++) {
                const float4* wr = (const float4*)&lds[(wv * 9 + g) * HID];
                float4 a = {0.f, 0.f, 0.f, 0.f};
                #pragma unroll
                for (int j = 0; j < 4; j++) {
                    float4 w = wr[64 * j + lane];
                    a.x += w.x * hr0[j].x; a.y += w.y * hr0[j].y;
                    a.z += w.z * hr0[j].z; a.w += w.w * hr0[j].w;
                }
                float acc = (a.x + a.y) + (a.z + a.w);
                #pragma unroll
                for (int off = 32; off; off >>= 1)
                    acc += __shfl_down(acc, off, 64);
                s[g] = acc;
            }
            if (lane == 0) {
                const float r = 1.f / (1.f + __expf(-(gc0 + s[0] + bh00)));
                const float z = 1.f / (1.f + __expf(-(gc1 + s[1] + bh01)));
                const float nn = tanhf(gc2 + r * (s[2] + bh02));
                const float hnew = (1.f - z) * nn + z * hprev0;
                hprev0 = hnew;
                const u64 v = ((u64)(unsigned)e << 32) | (u64)__float_as_uint(hnew);
                __hip_atomic_store(&hbuf0[(e & 1) * HID + d], v,
                                   __ATOMIC_RELAXED, __HIP_MEMORY_SCOPE_AGENT);
                gc0 = gn0; gc1 = gn1; gc2 = gn2;
            }
        }

        // ===== PHASE C: layer-1 h exchange — check relocated round 1,
        //       fallback pending-mask loop at the original point =====
        if (e == 1) {
            if (lane == 0) {
                const u64 v = ((u64)1u << 32) | (u64)__float_as_uint(hprev1);
                __hip_atomic_store(&hbuf1[HID + d], v,
                                   __ATOMIC_RELAXED, __HIP_MEMORY_SCOPE_AGENT);
            }
            __syncthreads();   // protect hl0 reads vs next epoch's writes
        } else {
            const unsigned te = (unsigned)(e - 1);
            bool dn[4];
            bool okC = true;
            #pragma unroll
            for (int j = 0; j < 4; j++) {
                dn[j] = ((unsigned)(vc[j] >> 32) == te);
                okC &= dn[j];
            }
            if (!okC) {
                const u64* sb = hbuf1 + ((e - 1) & 1) * HID;
                for (;;) {
                    #pragma unroll
                    for (int j = 0; j < 4; j++)
                        if (!dn[j])
                            vc[j] = __hip_atomic_load(&sb[tid + 256 * j], __ATOMIC_RELAXED,
                                                      __HIP_MEMORY_SCOPE_AGENT);
                    bool ok = true;
                    #pragma unroll
                    for (int j = 0; j < 4; j++) {
                        dn[j] = dn[j] || ((unsigned)(vc[j] >> 32) == te);
                        ok &= dn[j];
                    }
                    if (ok) break;
                    __builtin_amdgcn_s_sleep(1);
                }
            }
            #pragma unroll
            for (int j = 0; j < 4; j++)
                hl1[tid + 256 * j] = __uint_as_float((unsigned)vc[j]);
            __syncthreads();   // S2: all poll1 loads retired block-wide

            // ===== PHASE D: layer-1 compute + publish =====
            const float4* h1v4 = (const float4*)hl1;
            float4 hr1[4];
            #pragma unroll
            for (int j = 0; j < 4; j++) hr1[j] = h1v4[64 * j + lane];

            float si[3], sh[3];
            #pragma unroll
            for (int g = 0; g < 3; g++) {
                const float4* wi = (const float4*)&lds[(wv * 9 + 3 + g) * HID];
                const float4* wh = (const float4*)&lds[(wv * 9 + 6 + g) * HID];
                float4 a = {0.f, 0.f, 0.f, 0.f};
                float4 c = {0.f, 0.f, 0.f, 0.f};
                #pragma unroll
                for (int j = 0; j < 4; j++) {
                    float4 w1 = wi[64 * j + lane];
                    float4 w2 = wh[64 * j + lane];
                    a.x += w1.x * hr0[j].x; a.y += w1.y * hr0[j].y;
                    a.z += w1.z * hr0[j].z; a.w += w1.w * hr0[j].w;
                    c.x += w2.x * hr1[j].x; c.y += w2.y * hr1[j].y;
                    c.z += w2.z * hr1[j].z; c.w += w2.w * hr1[j].w;
                }
                float ai = (a.x + a.y) + (a.z + a.w);
                float ch = (c.x + c.y) + (c.z + c.w);
                #pragma unroll
                for (int off = 32; off; off >>= 1) {
                    ai += __shfl_down(ai, off, 64);
                    ch += __shfl_down(ch, off, 64);
                }
                si[g] = ai; sh[g] = ch;
            }
            if (lane == 0) {
                const float r = 1.f / (1.f + __expf(-(si[0] + bi10 + sh[0] + bh10)));
                const float z = 1.f / (1.f + __expf(-(si[1] + bi11 + sh[1] + bh11)));
                const float nn = tanhf(si[2] + bi12 + r * (sh[2] + bh12));
                const float hnew = (1.f - z) * nn + z * hprev1;
                hprev1 = hnew;
                if (e <= T) {
                    const u64 v = ((u64)(unsigned)e << 32) | (u64)__float_as_uint(hnew);
                    __hip_atomic_store(&hbuf1[(e & 1) * HID + d], v,
                                       __ATOMIC_RELAXED, __HIP_MEMORY_SCOPE_AGENT);
                } else {
                    hout[d] = hnew;   // e == T+1: final h1
                }
            }
        }
    }
}

// ---------------------------------------------------------------------------
// out[o] = dot(fc_W[o,:], h) + fc_b[o]; 64 waves, 16 outputs each.
// ---------------------------------------------------------------------------
__global__ __launch_bounds__(256) void fc_kernel(
    const float* __restrict__ h, const float* __restrict__ W,
    const float* __restrict__ b, float* __restrict__ out)
{
    __shared__ float hs[HID];
    const int wv = blockIdx.x * 4 + (threadIdx.x >> 6);
    const int lane = threadIdx.x & 63;
    for (int i = threadIdx.x; i < HID; i += 256) hs[i] = h[i];
    __syncthreads();
    for (int o = wv * 16; o < wv * 16 + 16; o++) {
        float acc = 0.f;
        #pragma unroll
        for (int u = 0; u < 16; u++)
            acc += W[(size_t)o * HID + lane + 64 * u] * hs[lane + 64 * u];
        #pragma unroll
        for (int off = 32; off; off >>= 1)
            acc += __shfl_down(acc, off, 64);
        if (lane == 0) out[o] = acc + b[o];
    }
}

// ---------------------------------------------------------------------------
extern "C" void kernel_launch(void* const* d_in, const int* in_sizes, int n_in,
                              void* d_out, int out_size, void* d_ws, size_t ws_size,
                              hipStream_t stream)
{
    const float* node_feats = (const float*)d_in[0];
    const int*   node_types = (const int*)d_in[1];
    const float* W1   = (const float*)d_in[2];
    const float* b1   = (const float*)d_in[3];
    const float* W2   = (const float*)d_in[4];
    const float* b2   = (const float*)d_in[5];
    const float* Wih0 = (const float*)d_in[6];
    const float* Whh0 = (const float*)d_in[7];
    const float* bih0 = (const float*)d_in[8];
    const float* bhh0 = (const float*)d_in[9];
    const float* Wih1 = (const float*)d_in[10];
    const float* Whh1 = (const float*)d_in[11];
    const float* bih1 = (const float*)d_in[12];
    const float* bhh1 = (const float*)d_in[13];
    const float* h_init = (const float*)d_in[14];
    const float* fc_W = (const float*)d_in[15];
    const float* fc_b = (const float*)d_in[16];
    float* out = (float*)d_out;

    char* ws = (char*)d_ws;
    const size_t GI_OFF    = 0;                      // 8192*3072*4 = 100663296
    const size_t EMB_OFF   = 100663296;              // 8192*512*4  = 16777216
    const size_t HOUT_OFF  = 117440512;              // 1024*4      = 4096
    const size_t HBUF0_OFF = 117444608;              // 2048*8      = 16384
    const size_t HBUF1_OFF = 117460992;              // 2048*8      = 16384

    float* gi   = (float*)(ws + GI_OFF);
    float* emb  = (float*)(ws + EMB_OFF);
    float* hout = (float*)(ws + HOUT_OFF);
    u64* hbuf0  = (u64*)(ws + HBUF0_OFF);
    u64* hbuf1  = (u64*)(ws + HBUF1_OFF);
    // hbufs start 0xAA-poisoned: tag 0xAAAAAAAA never matches an epoch in
    // [1, 8193], so no memset needed anywhere.

    // 1. Expert MLP -> emb [8192, 512]
    mlp_kernel<<<N_NODES, 256, 0, stream>>>(node_feats, node_types, W1, b1, W2, b2, emb);

    // 2. gi0 = emb @ Wih0^T + bih0  [8192, 3072]
    gemm_bt_bias<<<dim3(G3 / BN, N_NODES / BM), 256, 0, stream>>>(
        emb, Wih0, bih0, gi, N_NODES, G3, EMB);

    // 3. fused 2-layer scan (split-phase; phase-C round 1 hidden under B)
    gru_fused<<<256, 256, 0, stream>>>(gi, Whh0, bhh0, Wih1, bih1, Whh1, bhh1,
                                       h_init, hbuf0, hbuf1, hout, SEQ);

    // 4. FC on final hidden state
    fc_kernel<<<16, 256, 0, stream>>>(hout, fc_W, fc_b, out);
}

// Round 3
// 21599.779 us; speedup vs baseline: 2.2530x; 1.3284x over previous
//
#include <hip/hip_runtime.h>
#include <hip/hip_bf16.h>
#include <math.h>

typedef unsigned long long u64;

// Sizes
#define N_NODES 8192
#define IN_DIM 64
#define MLP_HID 128
#define EMB 512
#define HID 1024
#define G3 (3*HID)   // 3072
#define SEQ 8192

// ---------------------------------------------------------------------------
// Expert MLP: one block per node. h1 = relu(x@W1[t]+b1[t]); emb = h1@W2[t]+b2[t]
// ---------------------------------------------------------------------------
__global__ __launch_bounds__(256) void mlp_kernel(
    const float* __restrict__ x, const int* __restrict__ types,
    const float* __restrict__ W1, const float* __restrict__ b1,
    const float* __restrict__ W2, const float* __restrict__ b2,
    float* __restrict__ emb)
{
    __shared__ float xs[IN_DIM];
    __shared__ float h1[MLP_HID];
    const int n = blockIdx.x;
    const int ty = types[n];
    const int tid = threadIdx.x;

    if (tid < IN_DIM) xs[tid] = x[n * IN_DIM + tid];
    __syncthreads();

    if (tid < MLP_HID) {
        const float* w = W1 + (size_t)ty * IN_DIM * MLP_HID;
        float acc = b1[ty * MLP_HID + tid];
        #pragma unroll 8
        for (int k = 0; k < IN_DIM; k++)
            acc += xs[k] * w[k * MLP_HID + tid];
        h1[tid] = fmaxf(acc, 0.f);
    }
    __syncthreads();

    const float* w2 = W2 + (size_t)ty * MLP_HID * EMB;
    #pragma unroll
    for (int j = tid; j < EMB; j += 256) {
        float acc = b2[ty * EMB + j];
        #pragma unroll 8
        for (int k = 0; k < MLP_HID; k++)
            acc += h1[k] * w2[k * EMB + j];
        emb[(size_t)n * EMB + j] = acc;
    }
}

// ---------------------------------------------------------------------------
// C[M,N] = A[M,K] @ B[N,K]^T + bias[N]   (fp32, 64x64 tile, BK=16)
// ---------------------------------------------------------------------------
#define BM 64
#define BN 64
#define BK 16
__global__ __launch_bounds__(256) void gemm_bt_bias(
    const float* __restrict__ A, const float* __restrict__ B,
    const float* __restrict__ bias, float* __restrict__ C,
    int M, int N, int K)
{
    __shared__ float As[BK][BM + 1];
    __shared__ float Bs[BK][BN + 1];
    const int bm = blockIdx.y * BM, bn = blockIdx.x * BN;
    const int tid = threadIdx.x;
    const int tx = tid & 15, tyy = tid >> 4;   // 16x16 thread grid
    const int lr = tid >> 2;                   // loader row 0..63
    const int lk = (tid & 3) * 4;              // loader k offset

    float acc[4][4] = {};

    for (int k0 = 0; k0 < K; k0 += BK) {
        float4 av = *(const float4*)(A + (size_t)(bm + lr) * K + k0 + lk);
        float4 bv = *(const float4*)(B + (size_t)(bn + lr) * K + k0 + lk);
        As[lk + 0][lr] = av.x; As[lk + 1][lr] = av.y;
        As[lk + 2][lr] = av.z; As[lk + 3][lr] = av.w;
        Bs[lk + 0][lr] = bv.x; Bs[lk + 1][lr] = bv.y;
        Bs[lk + 2][lr] = bv.z; Bs[lk + 3][lr] = bv.w;
        __syncthreads();
        #pragma unroll
        for (int k = 0; k < BK; k++) {
            float a[4], b[4];
            #pragma unroll
            for (int i = 0; i < 4; i++) a[i] = As[k][tyy * 4 + i];
            #pragma unroll
            for (int j = 0; j < 4; j++) b[j] = Bs[k][tx * 4 + j];
            #pragma unroll
            for (int i = 0; i < 4; i++)
                #pragma unroll
                for (int j = 0; j < 4; j++)
                    acc[i][j] += a[i] * b[j];
        }
        __syncthreads();
    }

    #pragma unroll
    for (int i = 0; i < 4; i++) {
        const int row = bm + tyy * 4 + i;
        #pragma unroll
        for (int j = 0; j < 4; j++) {
            const int col = bn + tx * 4 + j;
            C[(size_t)row * N + col] = acc[i][j] + bias[col];
        }
    }
}

// ---------------------------------------------------------------------------
// Fused 2-layer GRU scan. 256 blocks (1/CU), 512 threads (8 waves, 2/SIMD).
//
// R12: CONCURRENT DUAL-ENGINE LOCKSTEP. Waves 0-3 = L0 engine, waves 4-7 =
// L1 engine. Per epoch:
//   1. eng0 polls hbuf0 tag e-1 -> hl0   CONCURRENT with
//      eng1 polls hbuf1 tag e-1 -> hl1   (the two coherent RTTs overlap)
//   2. S1 (block barrier): both LDS h-buffers valid
//   3. all waves snapshot hr0/hr1 registers; S2 (protects LDS vs next fill)
//   4. eng0: B compute (h0 update), publish h0 tag e    CONCURRENT with
//      eng1: D compute (h1 update),  publish h1 tag e
// D(e) consumes h0(e-1) (= hl0 of this epoch) and h1(e-1) — identical math
// to the sequential R9/R11 loop; D runs e in [2, T+1], B runs e in [1, T].
// hl1 at e<=2 is filled from h_init (replaces the old e==1 tag-1 bootstrap).
//
// Memory protocol per buffer is IDENTICAL to proven R9: per-word epoch
// tags, depth-2 ring, relaxed agent-scope 8B atomics, pending-mask poll +
// s_sleep backoff, publish gated behind the barrier that proves tag e-1
// consumption. Lockstep (block-wide barriers) means neither engine can lag,
// so the R9 anti-lap proof applies verbatim per buffer: X publishes tag e
// (slot e&1, overwriting e-2) only after X's poll of e-1 succeeded at
// S1(e); any Y published e-1 only after Y's S1(e-1), i.e. after Y's tag
// e-2 reads retired. Coherent-load count per step is UNCHANGED vs R9/R11
// (R10's lesson: loads may move, never duplicate).
// ---------------------------------------------------------------------------
#define WLDS_FLOATS (36 * 1024)          // 147456 B
#define HL0_OFF WLDS_FLOATS
#define HL1_OFF (WLDS_FLOATS + HID)

__global__ __launch_bounds__(512, 1) void gru_fused(
    const float* __restrict__ gi0,   // [T, 3072] layer-0 input gates (incl. bih0)
    const float* __restrict__ Whh0, const float* __restrict__ bhh0,
    const float* __restrict__ Wih1, const float* __restrict__ bih1,
    const float* __restrict__ Whh1, const float* __restrict__ bhh1,
    const float* __restrict__ h_init,   // [2, 1024]
    u64* __restrict__ hbuf0,            // [2][1024] tagged ring, layer 0
    u64* __restrict__ hbuf1,            // [2][1024] tagged ring, layer 1
    float* __restrict__ hout,           // [1024] final h1
    int T)
{
    __shared__ float lds[WLDS_FLOATS + 2 * HID];   // 155648 B

    const int tid = threadIdx.x;
    const int b = blockIdx.x;
    const int eng = tid >> 8;          // 0: L0 engine, 1: L1 engine
    const int etid = tid & 255;        // engine-local thread id
    const int wv = (tid >> 6) & 3;     // engine-local wave 0..3
    const int lane = tid & 63;
    const int d = b * 4 + wv;          // owned dim (per engine)

    float* hl0 = &lds[HL0_OFF];
    float* hl1 = &lds[HL1_OFF];

    // ---- stage 36 weight rows into LDS (once); layout: lds[(dl*9+r)*HID] ----
    for (int i = tid; i < 36 * 256; i += 512) {
        const int p = i >> 8;          // row 0..35 (= dl*9 + r)
        const int elem = i & 255;      // float4 index within the 1024-row
        const int dl = p / 9, r = p % 9;
        const int m = r / 3, g = r % 3;
        const float* src = (m == 0 ? Whh0 : (m == 1 ? Wih1 : Whh1))
                           + (size_t)(g * HID + b * 4 + dl) * HID;
        ((float4*)&lds[p * HID])[elem] = ((const float4*)src)[elem];
    }
    __syncthreads();

    // per-engine constants / state
    float bh00 = 0.f, bh01 = 0.f, bh02 = 0.f;
    float bi10 = 0.f, bi11 = 0.f, bi12 = 0.f;
    float bh10 = 0.f, bh11 = 0.f, bh12 = 0.f;
    float hprev0 = 0.f, hprev1 = 0.f;
    float gc0 = 0.f, gc1 = 0.f, gc2 = 0.f;
    if (eng == 0) {
        bh00 = bhh0[d]; bh01 = bhh0[HID + d]; bh02 = bhh0[2 * HID + d];
        if (lane == 0) {
            hprev0 = h_init[d];
            gc0 = gi0[d]; gc1 = gi0[HID + d]; gc2 = gi0[2 * HID + d];
        }
    } else {
        bi10 = bih1[d]; bi11 = bih1[HID + d]; bi12 = bih1[2 * HID + d];
        bh10 = bhh1[d]; bh11 = bhh1[HID + d]; bh12 = bhh1[2 * HID + d];
        if (lane == 0) hprev1 = h_init[HID + d];
    }

    for (int e = 1; e <= T + 1; e++) {
        // eng0 lane0: prefetch next epoch's gi0 row (in flight under polls)
        float gn0 = 0.f, gn1 = 0.f, gn2 = 0.f;
        if (eng == 0 && lane == 0 && e < T) {
            const float* g = gi0 + (size_t)e * G3;
            gn0 = g[d]; gn1 = g[HID + d]; gn2 = g[2 * HID + d];
        }

        // ===== concurrent POLL + FILL =====
        if (eng == 0) {
            if (e == 1) {
                #pragma unroll
                for (int j = 0; j < 4; j++)
                    hl0[etid + 256 * j] = h_init[etid + 256 * j];
            } else {
                const unsigned te = (unsigned)(e - 1);
                const u64* sa = hbuf0 + ((e - 1) & 1) * HID;
                u64 va[4];
                bool dn[4] = {false, false, false, false};
                for (;;) {
                    #pragma unroll
                    for (int j = 0; j < 4; j++)
                        if (!dn[j])
                            va[j] = __hip_atomic_load(&sa[etid + 256 * j], __ATOMIC_RELAXED,
                                                      __HIP_MEMORY_SCOPE_AGENT);
                    bool ok = true;
                    #pragma unroll
                    for (int j = 0; j < 4; j++) {
                        dn[j] = dn[j] || ((unsigned)(va[j] >> 32) == te);
                        ok &= dn[j];
                    }
                    if (ok) break;
                    __builtin_amdgcn_s_sleep(1);   // backoff: tame the poll storm
                }
                #pragma unroll
                for (int j = 0; j < 4; j++)
                    hl0[etid + 256 * j] = __uint_as_float((unsigned)va[j]);
            }
        } else {
            if (e <= 2) {
                // h1-state(e-1) for e in {1,2} is h_init layer 1
                #pragma unroll
                for (int j = 0; j < 4; j++)
                    hl1[etid + 256 * j] = h_init[HID + etid + 256 * j];
            } else {
                const unsigned te = (unsigned)(e - 1);
                const u64* sb = hbuf1 + ((e - 1) & 1) * HID;
                u64 vb[4];
                bool dn[4] = {false, false, false, false};
                for (;;) {
                    #pragma unroll
                    for (int j = 0; j < 4; j++)
                        if (!dn[j])
                            vb[j] = __hip_atomic_load(&sb[etid + 256 * j], __ATOMIC_RELAXED,
                                                      __HIP_MEMORY_SCOPE_AGENT);
                    bool ok = true;
                    #pragma unroll
                    for (int j = 0; j < 4; j++) {
                        dn[j] = dn[j] || ((unsigned)(vb[j] >> 32) == te);
                        ok &= dn[j];
                    }
                    if (ok) break;
                    __builtin_amdgcn_s_sleep(1);
                }
                #pragma unroll
                for (int j = 0; j < 4; j++)
                    hl1[etid + 256 * j] = __uint_as_float((unsigned)vb[j]);
            }
        }
        __syncthreads();   // S1: hl0 AND hl1 valid block-wide

        // ===== register snapshots (before S2 so next fill can't clobber) =====
        const float4* h0v4 = (const float4*)hl0;
        float4 hr0[4];
        #pragma unroll
        for (int j = 0; j < 4; j++) hr0[j] = h0v4[64 * j + lane];
        float4 hr1[4] = {};
        if (eng == 1) {
            const float4* h1v4 = (const float4*)hl1;
            #pragma unroll
            for (int j = 0; j < 4; j++) hr1[j] = h1v4[64 * j + lane];
        }
        __syncthreads();   // S2: all LDS reads retired; fills of e+1 are safe

        if (eng == 0) {
            // ===== L0 engine: B compute + publish (e <= T) =====
            if (e <= T) {
                float s[3];
                #pragma unroll
                for (int g = 0; g < 3; g++) {
                    const float4* wr = (const float4*)&lds[(wv * 9 + g) * HID];
                    float4 a = {0.f, 0.f, 0.f, 0.f};
                    #pragma unroll
                    for (int j = 0; j < 4; j++) {
                        float4 w = wr[64 * j + lane];
                        a.x += w.x * hr0[j].x; a.y += w.y * hr0[j].y;
                        a.z += w.z * hr0[j].z; a.w += w.w * hr0[j].w;
                    }
                    float acc = (a.x + a.y) + (a.z + a.w);
                    #pragma unroll
                    for (int off = 32; off; off >>= 1)
                        acc += __shfl_down(acc, off, 64);
                    s[g] = acc;
                }
                if (lane == 0) {
                    const float r = 1.f / (1.f + __expf(-(gc0 + s[0] + bh00)));
                    const float z = 1.f / (1.f + __expf(-(gc1 + s[1] + bh01)));
                    const float nn = tanhf(gc2 + r * (s[2] + bh02));
                    const float hnew = (1.f - z) * nn + z * hprev0;
                    hprev0 = hnew;
                    const u64 v = ((u64)(unsigned)e << 32) | (u64)__float_as_uint(hnew);
                    __hip_atomic_store(&hbuf0[(e & 1) * HID + d], v,
                                       __ATOMIC_RELAXED, __HIP_MEMORY_SCOPE_AGENT);
                    gc0 = gn0; gc1 = gn1; gc2 = gn2;
                }
            }
        } else {
            // ===== L1 engine: D compute + publish (e >= 2) =====
            if (e >= 2) {
                float si[3], sh[3];
                #pragma unroll
                for (int g = 0; g < 3; g++) {
                    const float4* wi = (const float4*)&lds[(wv * 9 + 3 + g) * HID];
                    const float4* wh = (const float4*)&lds[(wv * 9 + 6 + g) * HID];
                    float4 a = {0.f, 0.f, 0.f, 0.f};
                    float4 c = {0.f, 0.f, 0.f, 0.f};
                    #pragma unroll
                    for (int j = 0; j < 4; j++) {
                        float4 w1 = wi[64 * j + lane];
                        float4 w2 = wh[64 * j + lane];
                        a.x += w1.x * hr0[j].x; a.y += w1.y * hr0[j].y;
                        a.z += w1.z * hr0[j].z; a.w += w1.w * hr0[j].w;
                        c.x += w2.x * hr1[j].x; c.y += w2.y * hr1[j].y;
                        c.z += w2.z * hr1[j].z; c.w += w2.w * hr1[j].w;
                    }
                    float ai = (a.x + a.y) + (a.z + a.w);
                    float ch = (c.x + c.y) + (c.z + c.w);
                    #pragma unroll
                    for (int off = 32; off; off >>= 1) {
                        ai += __shfl_down(ai, off, 64);
                        ch += __shfl_down(ch, off, 64);
                    }
                    si[g] = ai; sh[g] = ch;
                }
                if (lane == 0) {
                    const float r = 1.f / (1.f + __expf(-(si[0] + bi10 + sh[0] + bh10)));
                    const float z = 1.f / (1.f + __expf(-(si[1] + bi11 + sh[1] + bh11)));
                    const float nn = tanhf(si[2] + bi12 + r * (sh[2] + bh12));
                    const float hnew = (1.f - z) * nn + z * hprev1;
                    hprev1 = hnew;
                    if (e <= T) {
                        const u64 v = ((u64)(unsigned)e << 32) | (u64)__float_as_uint(hnew);
                        __hip_atomic_store(&hbuf1[(e & 1) * HID + d], v,
                                           __ATOMIC_RELAXED, __HIP_MEMORY_SCOPE_AGENT);
                    } else {
                        hout[d] = hnew;   // e == T+1: final h1
                    }
                }
            }
        }
    }
}

// ---------------------------------------------------------------------------
// out[o] = dot(fc_W[o,:], h) + fc_b[o]; 64 waves, 16 outputs each.
// ---------------------------------------------------------------------------
__global__ __launch_bounds__(256) void fc_kernel(
    const float* __restrict__ h, const float* __restrict__ W,
    const float* __restrict__ b, float* __restrict__ out)
{
    __shared__ float hs[HID];
    const int wv = blockIdx.x * 4 + (threadIdx.x >> 6);
    const int lane = threadIdx.x & 63;
    for (int i = threadIdx.x; i < HID; i += 256) hs[i] = h[i];
    __syncthreads();
    for (int o = wv * 16; o < wv * 16 + 16; o++) {
        float acc = 0.f;
        #pragma unroll
        for (int u = 0; u < 16; u++)
            acc += W[(size_t)o * HID + lane + 64 * u] * hs[lane + 64 * u];
        #pragma unroll
        for (int off = 32; off; off >>= 1)
            acc += __shfl_down(acc, off, 64);
        if (lane == 0) out[o] = acc + b[o];
    }
}

// ---------------------------------------------------------------------------
extern "C" void kernel_launch(void* const* d_in, const int* in_sizes, int n_in,
                              void* d_out, int out_size, void* d_ws, size_t ws_size,
                              hipStream_t stream)
{
    const float* node_feats = (const float*)d_in[0];
    const int*   node_types = (const int*)d_in[1];
    const float* W1   = (const float*)d_in[2];
    const float* b1   = (const float*)d_in[3];
    const float* W2   = (const float*)d_in[4];
    const float* b2   = (const float*)d_in[5];
    const float* Wih0 = (const float*)d_in[6];
    const float* Whh0 = (const float*)d_in[7];
    const float* bih0 = (const float*)d_in[8];
    const float* bhh0 = (const float*)d_in[9];
    const float* Wih1 = (const float*)d_in[10];
    const float* Whh1 = (const float*)d_in[11];
    const float* bih1 = (const float*)d_in[12];
    const float* bhh1 = (const float*)d_in[13];
    const float* h_init = (const float*)d_in[14];
    const float* fc_W = (const float*)d_in[15];
    const float* fc_b = (const float*)d_in[16];
    float* out = (float*)d_out;

    char* ws = (char*)d_ws;
    const size_t GI_OFF    = 0;                      // 8192*3072*4 = 100663296
    const size_t EMB_OFF   = 100663296;              // 8192*512*4  = 16777216
    const size_t HOUT_OFF  = 117440512;              // 1024*4      = 4096
    const size_t HBUF0_OFF = 117444608;              // 2048*8      = 16384
    const size_t HBUF1_OFF = 117460992;              // 2048*8      = 16384

    float* gi   = (float*)(ws + GI_OFF);
    float* emb  = (float*)(ws + EMB_OFF);
    float* hout = (float*)(ws + HOUT_OFF);
    u64* hbuf0  = (u64*)(ws + HBUF0_OFF);
    u64* hbuf1  = (u64*)(ws + HBUF1_OFF);
    // hbufs start 0xAA-poisoned: tag 0xAAAAAAAA never matches an epoch in
    // [1, 8193], so no memset needed anywhere.

    // 1. Expert MLP -> emb [8192, 512]
    mlp_kernel<<<N_NODES, 256, 0, stream>>>(node_feats, node_types, W1, b1, W2, b2, emb);

    // 2. gi0 = emb @ Wih0^T + bih0  [8192, 3072]
    gemm_bt_bias<<<dim3(G3 / BN, N_NODES / BM), 256, 0, stream>>>(
        emb, Wih0, bih0, gi, N_NODES, G3, EMB);

    // 3. fused 2-layer scan (concurrent dual-engine lockstep, 512 thr)
    gru_fused<<<256, 512, 0, stream>>>(gi, Whh0, bhh0, Wih1, bih1, Whh1, bhh1,
                                       h_init, hbuf0, hbuf1, hout, SEQ);

    // 4. FC on final hidden state
    fc_kernel<<<16, 256, 0, stream>>>(hout, fc_W, fc_b, out);
}